// Round 2
// 1227.694 us; speedup vs baseline: 1.0750x; 1.0750x over previous
//
#include <hip/hip_runtime.h>
#include <hip/hip_bf16.h>
#include <stdint.h>

#define N_ROWS 2048
#define DK 1024
#define NU 50257
#define NS 8192

typedef __bf16 bf16x8 __attribute__((ext_vector_type(8)));
typedef float f32x4 __attribute__((ext_vector_type(4)));
typedef float vf4 __attribute__((ext_vector_type(4)));   // clang-native for nt builtins
typedef unsigned vu2 __attribute__((ext_vector_type(2)));
typedef unsigned vu4 __attribute__((ext_vector_type(4)));

__device__ __forceinline__ unsigned short f2bf_rne(float f) {
  union { float f; unsigned u; } v; v.f = f;
  unsigned u = v.u;
  return (unsigned short)((u + 0x7FFFu + ((u >> 16) & 1u)) >> 16);
}
__device__ __forceinline__ unsigned pack2(float lo, float hi) {
  return (unsigned)f2bf_rne(lo) | ((unsigned)f2bf_rne(hi) << 16);
}

// ---------- fp32 -> bf16 bulk convert (8 elems/thread, 16B stores) ----------
// nt loads: the fp32 source is dead after this pass; keep L2/L3 for the bf16
// output (which gemm_probs re-reads).
__global__ void cvt_f32_bf16(const float* __restrict__ in,
                             unsigned short* __restrict__ out, unsigned n) {
  unsigned i = (blockIdx.x * 256u + threadIdx.x) * 8u;
  if (i >= n) return;
  const vf4* p = (const vf4*)(in + i);
  vf4 a = __builtin_nontemporal_load(p);
  vf4 b = __builtin_nontemporal_load(p + 1);
  vu4 o;
  o.x = pack2(a.x, a.y); o.y = pack2(a.z, a.w);
  o.z = pack2(b.x, b.y); o.w = pack2(b.z, b.w);
  *(vu4*)(out + i) = o;
}

// ---------- gather sampled rows to bf16 + per-col adjust term ----------
__global__ void gather_sampled(const float* __restrict__ kern,
                               const float* __restrict__ bias,
                               const int* __restrict__ sampled,
                               unsigned short* __restrict__ sw,
                               float* __restrict__ adj) {
  int j = blockIdx.x;
  int s = sampled[j];
  const float* src = kern + (size_t)s * DK;
  unsigned short* dst = sw + (size_t)j * DK;
  int c = threadIdx.x * 4;  // 256*4 == 1024
  vf4 v = __builtin_nontemporal_load((const vf4*)(src + c));
  vu2 o; o.x = pack2(v.x, v.y); o.y = pack2(v.z, v.w);
  *(vu2*)(dst + c) = o;
  if (threadIdx.x == 0) {
    // adj = bias[s] - (log(S) + logq(s)),  logq = log(log1p(1/(s+1))) - log(log(U+1))
    float lq = logf(log1pf(1.0f / ((float)s + 1.0f))) - logf(logf((float)(NU + 1)));
    adj[j] = bias[s] - (logf((float)NS) + lq);
  }
}

// ---------- true logit per row (fp32 dot), adds exp(tl) into loss accum ----------
__global__ void true_logits_k(const float* __restrict__ x, const float* __restrict__ kern,
                              const float* __restrict__ bias, const int* __restrict__ targets,
                              float* __restrict__ true_logit, float* __restrict__ loss_acc) {
  int row = blockIdx.x * 4 + (threadIdx.x >> 6);
  int lane = threadIdx.x & 63;
  int t = targets[row];
  const float* xr = x + (size_t)row * DK;
  const float* wr = kern + (size_t)t * DK;
  float s = 0.f;
  #pragma unroll
  for (int it = 0; it < 4; ++it) {
    int c = lane * 4 + it * 256;
    float4 a = *(const float4*)(xr + c);
    float4 b = *(const float4*)(wr + c);
    s += a.x * b.x + a.y * b.y + a.z * b.z + a.w * b.w;
  }
  #pragma unroll
  for (int off = 32; off > 0; off >>= 1) s += __shfl_xor(s, off, 64);
  if (lane == 0) {
    float lq = logf(log1pf(1.0f / ((float)t + 1.0f))) - logf(logf((float)(NU + 1)));
    float tl = s + bias[t] - (logf((float)NS) + lq);
    true_logit[row] = tl;
    atomicAdd(&loss_acc[row], __expf(tl));
  }
}

// ---------- main GEMM: probs numerator + row sums (m97 structure) ----------
// 1-D grid of 6288 blocks. Swizzle: each XCD gets a contiguous chunk of 786
// tiles (6288 = 8*786, bijective), ordered row-inner (16 row-tiles of one
// column panel consecutive) so each 262 KB B-panel is fetched once per XCD-L2
// and reused 16x; A (4 MB bf16) stays L2-resident.
__global__ __launch_bounds__(256) void gemm_probs(
    const unsigned short* __restrict__ A,   // x bf16 [2048,1024]
    const unsigned short* __restrict__ Bm,  // kernel bf16 [NU,1024]
    const float* __restrict__ bias,
    float* __restrict__ out, float* __restrict__ row_sum) {
  __shared__ alignas(16) unsigned short As[128 * 32];
  __shared__ alignas(16) unsigned short Bs[128 * 32];
  const int tid = threadIdx.x;
  const int wave = tid >> 6, lane = tid & 63;
  const int bid = blockIdx.x;
  const int sb = (bid & 7) * 786 + (bid >> 3);   // XCD-chunk swizzle
  const int rb = (sb & 15) << 7;                 // row tile (inner)
  const int cb = (sb >> 4) << 7;                 // col panel (outer)
  const int wm = wave & 1, wn = wave >> 1;
  const int q = lane >> 4, l15 = lane & 15;
  const int srow = lane >> 2, scol = lane & 3;

  f32x4 acc[4][4] = {};

  const int seg0 = wave * 2;
  const unsigned short* ga0 = A + (size_t)(rb + seg0 * 16 + srow) * DK + scol * 8;
  const unsigned short* ga1 = ga0 + (size_t)16 * DK;
  int bu0 = cb + seg0 * 16 + srow;       if (bu0 > NU - 1) bu0 = NU - 1;
  int bu1 = cb + (seg0 + 1) * 16 + srow; if (bu1 > NU - 1) bu1 = NU - 1;
  const unsigned short* gb0 = Bm + (size_t)bu0 * DK + scol * 8;
  const unsigned short* gb1 = Bm + (size_t)bu1 * DK + scol * 8;
  unsigned short* la0 = &As[(seg0) * 512];
  unsigned short* la1 = &As[(seg0 + 1) * 512];
  unsigned short* lb0 = &Bs[(seg0) * 512];
  unsigned short* lb1 = &Bs[(seg0 + 1) * 512];

  for (int kb = 0; kb < DK; kb += 32) {
    __builtin_amdgcn_global_load_lds((__attribute__((address_space(1))) void*)(ga0 + kb),
                                     (__attribute__((address_space(3))) void*)la0, 16, 0, 0);
    __builtin_amdgcn_global_load_lds((__attribute__((address_space(1))) void*)(ga1 + kb),
                                     (__attribute__((address_space(3))) void*)la1, 16, 0, 0);
    __builtin_amdgcn_global_load_lds((__attribute__((address_space(1))) void*)(gb0 + kb),
                                     (__attribute__((address_space(3))) void*)lb0, 16, 0, 0);
    __builtin_amdgcn_global_load_lds((__attribute__((address_space(1))) void*)(gb1 + kb),
                                     (__attribute__((address_space(3))) void*)lb1, 16, 0, 0);
    __syncthreads();
    bf16x8 af[4], bfr[4];
    #pragma unroll
    for (int mi = 0; mi < 4; ++mi)
      af[mi] = *(const bf16x8*)&As[(wm * 64 + mi * 16 + l15) * 32 + q * 8];
    #pragma unroll
    for (int ni = 0; ni < 4; ++ni)
      bfr[ni] = *(const bf16x8*)&Bs[(wn * 64 + ni * 16 + l15) * 32 + q * 8];
    #pragma unroll
    for (int mi = 0; mi < 4; ++mi)
      #pragma unroll
      for (int ni = 0; ni < 4; ++ni)
        acc[mi][ni] = __builtin_amdgcn_mfma_f32_16x16x32_bf16(af[mi], bfr[ni], acc[mi][ni], 0, 0, 0);
    __syncthreads();
  }

  #pragma unroll
  for (int mi = 0; mi < 4; ++mi) {
    int row0 = rb + wm * 64 + mi * 16 + q * 4;
    float rs[4] = {0.f, 0.f, 0.f, 0.f};
    #pragma unroll
    for (int ni = 0; ni < 4; ++ni) {
      int col = cb + wn * 64 + ni * 16 + l15;
      if (col < NU) {
        float bv = bias[col];
        f32x4 c = acc[mi][ni];
        #pragma unroll
        for (int r = 0; r < 4; ++r) {
          float p = __expf(c[r] + bv);
          // nt store: 412 MB one-shot stream must not evict B panels from L2/L3
          __builtin_nontemporal_store(p, &out[(size_t)(row0 + r) * NU + col]);
          rs[r] += p;
        }
      }
    }
    #pragma unroll
    for (int r = 0; r < 4; ++r) {
      float v = rs[r];
      v += __shfl_xor(v, 1, 64);
      v += __shfl_xor(v, 2, 64);
      v += __shfl_xor(v, 4, 64);
      v += __shfl_xor(v, 8, 64);
      if (l15 == 0) atomicAdd(&row_sum[row0 + r], v);
    }
  }
}

// ---------- sampled GEMM: fused exp-sum with accidental-hit masking ----------
// Same swizzle: 1024 blocks = 8 * 128.
__global__ __launch_bounds__(256) void gemm_sampled(
    const unsigned short* __restrict__ A, const unsigned short* __restrict__ SW,
    const float* __restrict__ adj, const int* __restrict__ sampled,
    const int* __restrict__ targets, float* __restrict__ loss_acc) {
  __shared__ alignas(16) unsigned short As[128 * 32];
  __shared__ alignas(16) unsigned short Bs[128 * 32];
  const int tid = threadIdx.x;
  const int wave = tid >> 6, lane = tid & 63;
  const int bid = blockIdx.x;
  const int sb = (bid & 7) * 128 + (bid >> 3);
  const int rb = (sb & 15) << 7;
  const int cb = (sb >> 4) << 7;
  const int wm = wave & 1, wn = wave >> 1;
  const int q = lane >> 4, l15 = lane & 15;
  const int srow = lane >> 2, scol = lane & 3;

  f32x4 acc[4][4] = {};

  const int seg0 = wave * 2;
  const unsigned short* ga0 = A + (size_t)(rb + seg0 * 16 + srow) * DK + scol * 8;
  const unsigned short* ga1 = ga0 + (size_t)16 * DK;
  const unsigned short* gb0 = SW + (size_t)(cb + seg0 * 16 + srow) * DK + scol * 8;
  const unsigned short* gb1 = gb0 + (size_t)16 * DK;
  unsigned short* la0 = &As[(seg0) * 512];
  unsigned short* la1 = &As[(seg0 + 1) * 512];
  unsigned short* lb0 = &Bs[(seg0) * 512];
  unsigned short* lb1 = &Bs[(seg0 + 1) * 512];

  for (int kb = 0; kb < DK; kb += 32) {
    __builtin_amdgcn_global_load_lds((__attribute__((address_space(1))) void*)(ga0 + kb),
                                     (__attribute__((address_space(3))) void*)la0, 16, 0, 0);
    __builtin_amdgcn_global_load_lds((__attribute__((address_space(1))) void*)(ga1 + kb),
                                     (__attribute__((address_space(3))) void*)la1, 16, 0, 0);
    __builtin_amdgcn_global_load_lds((__attribute__((address_space(1))) void*)(gb0 + kb),
                                     (__attribute__((address_space(3))) void*)lb0, 16, 0, 0);
    __builtin_amdgcn_global_load_lds((__attribute__((address_space(1))) void*)(gb1 + kb),
                                     (__attribute__((address_space(3))) void*)lb1, 16, 0, 0);
    __syncthreads();
    bf16x8 af[4], bfr[4];
    #pragma unroll
    for (int mi = 0; mi < 4; ++mi)
      af[mi] = *(const bf16x8*)&As[(wm * 64 + mi * 16 + l15) * 32 + q * 8];
    #pragma unroll
    for (int ni = 0; ni < 4; ++ni)
      bfr[ni] = *(const bf16x8*)&Bs[(wn * 64 + ni * 16 + l15) * 32 + q * 8];
    #pragma unroll
    for (int mi = 0; mi < 4; ++mi)
      #pragma unroll
      for (int ni = 0; ni < 4; ++ni)
        acc[mi][ni] = __builtin_amdgcn_mfma_f32_16x16x32_bf16(af[mi], bfr[ni], acc[mi][ni], 0, 0, 0);
    __syncthreads();
  }

  #pragma unroll
  for (int mi = 0; mi < 4; ++mi) {
    int row0 = rb + wm * 64 + mi * 16 + q * 4;
    int t0 = targets[row0], t1 = targets[row0 + 1], t2 = targets[row0 + 2], t3 = targets[row0 + 3];
    float rs[4] = {0.f, 0.f, 0.f, 0.f};
    #pragma unroll
    for (int ni = 0; ni < 4; ++ni) {
      int col = cb + wn * 64 + ni * 16 + l15;
      float av = adj[col];
      int sid = sampled[col];
      f32x4 c = acc[mi][ni];
      rs[0] += (sid == t0) ? 0.f : __expf(c[0] + av);
      rs[1] += (sid == t1) ? 0.f : __expf(c[1] + av);
      rs[2] += (sid == t2) ? 0.f : __expf(c[2] + av);
      rs[3] += (sid == t3) ? 0.f : __expf(c[3] + av);
    }
    #pragma unroll
    for (int r = 0; r < 4; ++r) {
      float v = rs[r];
      v += __shfl_xor(v, 1, 64);
      v += __shfl_xor(v, 2, 64);
      v += __shfl_xor(v, 4, 64);
      v += __shfl_xor(v, 8, 64);
      if (l15 == 0) atomicAdd(&loss_acc[row0 + r], v);
    }
  }
}

// ---------- 1/row_sum ----------
__global__ void prep_inv(const float* __restrict__ row_sum, float* __restrict__ inv) {
  int i = blockIdx.x * 256 + threadIdx.x;
  if (i < N_ROWS) inv[i] = 1.0f / row_sum[i];
}

// ---------- scale probs in place (nt: pure stream, no reuse) ----------
__global__ void scale_probs(float* __restrict__ out, const float* __restrict__ inv, unsigned n4) {
  unsigned i = blockIdx.x * 256u + threadIdx.x;
  if (i >= n4) return;
  constexpr unsigned long long MAGIC = ((1ull << 45) + 50256ull) / 50257ull;
  vf4 v = __builtin_nontemporal_load((const vf4*)out + i);
  unsigned long long base = (unsigned long long)i * 4ull;
  unsigned r0 = (unsigned)((base * MAGIC) >> 45);
  unsigned r1 = (unsigned)(((base + 1) * MAGIC) >> 45);
  unsigned r2 = (unsigned)(((base + 2) * MAGIC) >> 45);
  unsigned r3 = (unsigned)(((base + 3) * MAGIC) >> 45);
  v.x *= inv[r0]; v.y *= inv[r1]; v.z *= inv[r2]; v.w *= inv[r3];
  __builtin_nontemporal_store(v, (vf4*)out + i);
}

// ---------- final loss reduce ----------
__global__ void finalize_loss(const float* __restrict__ loss_acc,
                              const float* __restrict__ true_logit,
                              float* __restrict__ loss_out) {
  __shared__ float red[256];
  float s = 0.f;
  for (int i = threadIdx.x; i < N_ROWS; i += 256)
    s += logf(loss_acc[i]) - true_logit[i];
  red[threadIdx.x] = s;
  __syncthreads();
  for (int off = 128; off > 0; off >>= 1) {
    if (threadIdx.x < off) red[threadIdx.x] += red[threadIdx.x + off];
    __syncthreads();
  }
  if (threadIdx.x == 0) loss_out[0] = red[0] / (float)N_ROWS;
}

extern "C" void kernel_launch(void* const* d_in, const int* in_sizes, int n_in,
                              void* d_out, int out_size, void* d_ws, size_t ws_size,
                              hipStream_t stream) {
  const float* x = (const float*)d_in[0];       // [2,1024,1024]
  const float* kern = (const float*)d_in[1];    // [50257,1024]
  const float* bias = (const float*)d_in[2];    // [50257]
  const int* targets = (const int*)d_in[3];     // [2048]
  const int* sampled = (const int*)d_in[4];     // [8192]
  float* out = (float*)d_out;                   // probs [2048*50257] then loss [1]

  char* ws = (char*)d_ws;
  size_t off = 0;
  unsigned short* kbf = (unsigned short*)(ws + off); off += (size_t)NU * DK * 2;     // 98.2 MiB
  unsigned short* xbf = (unsigned short*)(ws + off); off += (size_t)N_ROWS * DK * 2; // 4 MiB
  unsigned short* swbf = (unsigned short*)(ws + off); off += (size_t)NS * DK * 2;    // 16 MiB
  float* adj = (float*)(ws + off); off += (size_t)NS * 4;
  float* row_sum = (float*)(ws + off); off += (size_t)N_ROWS * 4;
  float* inv_rs = (float*)(ws + off); off += (size_t)N_ROWS * 4;
  float* loss_acc = (float*)(ws + off); off += (size_t)N_ROWS * 4;
  float* true_l = (float*)(ws + off); off += (size_t)N_ROWS * 4;

  hipMemsetAsync(row_sum, 0, N_ROWS * 4, stream);
  hipMemsetAsync(loss_acc, 0, N_ROWS * 4, stream);

  {
    unsigned n = NU * DK;  // 51,463,168 (divisible by 8)
    cvt_f32_bf16<<<(n / 8 + 255) / 256, 256, 0, stream>>>(kern, kbf, n);
  }
  {
    unsigned n = N_ROWS * DK;
    cvt_f32_bf16<<<(n / 8 + 255) / 256, 256, 0, stream>>>(x, xbf, n);
  }
  gather_sampled<<<NS, 256, 0, stream>>>(kern, bias, sampled, swbf, adj);
  true_logits_k<<<N_ROWS / 4, 256, 0, stream>>>(x, kern, bias, targets, true_l, loss_acc);

  // 393 col panels x 16 row tiles = 6288 blocks (= 8 XCD chunks of 786)
  gemm_probs<<<dim3(6288), 256, 0, stream>>>(xbf, kbf, bias, out, row_sum);

  // 64 col panels x 16 row tiles = 1024 blocks (= 8 XCD chunks of 128)
  gemm_sampled<<<dim3(1024), 256, 0, stream>>>(xbf, swbf, adj, sampled, targets, loss_acc);

  prep_inv<<<(N_ROWS + 255) / 256, 256, 0, stream>>>(row_sum, inv_rs);

  {
    unsigned n4 = (unsigned)(((size_t)N_ROWS * NU) / 4);  // 25,731,584 (exact)
    scale_probs<<<(n4 + 255u) / 256u, 256, 0, stream>>>(out, inv_rs, n4);
  }
  finalize_loss<<<1, 256, 0, stream>>>(loss_acc, true_l, out + (size_t)N_ROWS * NU);
}

// Round 3
// 1031.102 us; speedup vs baseline: 1.2799x; 1.1907x over previous
//
#include <hip/hip_runtime.h>
#include <hip/hip_bf16.h>
#include <stdint.h>

#define N_ROWS 2048
#define DK 1024
#define NU 50257
#define NS 8192

typedef __bf16 bf16x8 __attribute__((ext_vector_type(8)));
typedef float f32x4 __attribute__((ext_vector_type(4)));
typedef float vf4 __attribute__((ext_vector_type(4)));   // clang-native for nt builtins
typedef unsigned vu2 __attribute__((ext_vector_type(2)));
typedef unsigned vu4 __attribute__((ext_vector_type(4)));

__device__ __forceinline__ unsigned short f2bf_rne(float f) {
  union { float f; unsigned u; } v; v.f = f;
  unsigned u = v.u;
  return (unsigned short)((u + 0x7FFFu + ((u >> 16) & 1u)) >> 16);
}
__device__ __forceinline__ unsigned pack2(float lo, float hi) {
  return (unsigned)f2bf_rne(lo) | ((unsigned)f2bf_rne(hi) << 16);
}

// ---------- fp32 -> bf16 bulk convert (8 elems/thread, 16B stores) ----------
__global__ void cvt_f32_bf16(const float* __restrict__ in,
                             unsigned short* __restrict__ out, unsigned n) {
  unsigned i = (blockIdx.x * 256u + threadIdx.x) * 8u;
  if (i >= n) return;
  const vf4* p = (const vf4*)(in + i);
  vf4 a = __builtin_nontemporal_load(p);
  vf4 b = __builtin_nontemporal_load(p + 1);
  vu4 o;
  o.x = pack2(a.x, a.y); o.y = pack2(a.z, a.w);
  o.z = pack2(b.x, b.y); o.w = pack2(b.z, b.w);
  *(vu4*)(out + i) = o;
}

// ---------- gather sampled rows to bf16 + per-col adjust term ----------
__global__ void gather_sampled(const float* __restrict__ kern,
                               const float* __restrict__ bias,
                               const int* __restrict__ sampled,
                               unsigned short* __restrict__ sw,
                               float* __restrict__ adj) {
  int j = blockIdx.x;
  int s = sampled[j];
  const float* src = kern + (size_t)s * DK;
  unsigned short* dst = sw + (size_t)j * DK;
  int c = threadIdx.x * 4;  // 256*4 == 1024
  vf4 v = __builtin_nontemporal_load((const vf4*)(src + c));
  vu2 o; o.x = pack2(v.x, v.y); o.y = pack2(v.z, v.w);
  *(vu2*)(dst + c) = o;
  if (threadIdx.x == 0) {
    float lq = logf(log1pf(1.0f / ((float)s + 1.0f))) - logf(logf((float)(NU + 1)));
    adj[j] = bias[s] - (logf((float)NS) + lq);
  }
}

// ---------- true logit per row (fp32 dot), adds exp(tl) into loss accum ----------
__global__ void true_logits_k(const float* __restrict__ x, const float* __restrict__ kern,
                              const float* __restrict__ bias, const int* __restrict__ targets,
                              float* __restrict__ true_logit, float* __restrict__ loss_acc) {
  int row = blockIdx.x * 4 + (threadIdx.x >> 6);
  int lane = threadIdx.x & 63;
  int t = targets[row];
  const float* xr = x + (size_t)row * DK;
  const float* wr = kern + (size_t)t * DK;
  float s = 0.f;
  #pragma unroll
  for (int it = 0; it < 4; ++it) {
    int c = lane * 4 + it * 256;
    float4 a = *(const float4*)(xr + c);
    float4 b = *(const float4*)(wr + c);
    s += a.x * b.x + a.y * b.y + a.z * b.z + a.w * b.w;
  }
  #pragma unroll
  for (int off = 32; off > 0; off >>= 1) s += __shfl_xor(s, off, 64);
  if (lane == 0) {
    float lq = logf(log1pf(1.0f / ((float)t + 1.0f))) - logf(logf((float)(NU + 1)));
    float tl = s + bias[t] - (logf((float)NS) + lq);
    true_logit[row] = tl;
    atomicAdd(&loss_acc[row], __expf(tl));
  }
}

// ---------- main GEMM: probs numerator + row sums ----------
// XCD-chunk swizzle (6288 = 8*786, bijective), row-inner so each B panel is
// L2-reused 16x. Epilogue: LDS-staged 32x128 tile (reusing dead As/Bs memory)
// -> coalesced 128B-per-8-lane nt float4 stores, row sums on read-back.
__global__ __launch_bounds__(256) void gemm_probs(
    const unsigned short* __restrict__ A,   // x bf16 [2048,1024]
    const unsigned short* __restrict__ Bm,  // kernel bf16 [NU,1024]
    const float* __restrict__ bias,
    float* __restrict__ out, float* __restrict__ row_sum) {
  // 16.5 KiB shared: K-loop uses it as As(8K)+Bs(8K); epilogue reuses it as
  // a 32x132 fp32 output tile (132 = +4 pad -> bank spread across rows).
  __shared__ alignas(16) unsigned char smem[32 * 132 * 4];
  unsigned short* As = (unsigned short*)smem;
  unsigned short* Bs = (unsigned short*)(smem + 8192);
  float* ot = (float*)smem;

  const int tid = threadIdx.x;
  const int wave = tid >> 6, lane = tid & 63;
  const int bid = blockIdx.x;
  const int sb = (bid & 7) * 786 + (bid >> 3);   // XCD-chunk swizzle
  const int rb = (sb & 15) << 7;                 // row tile (inner)
  const int cb = (sb >> 4) << 7;                 // col panel (outer)
  const int wm = wave & 1, wn = wave >> 1;
  const int q = lane >> 4, l15 = lane & 15;
  const int srow = lane >> 2, scol = lane & 3;

  f32x4 acc[4][4] = {};

  const int seg0 = wave * 2;
  const unsigned short* ga0 = A + (size_t)(rb + seg0 * 16 + srow) * DK + scol * 8;
  const unsigned short* ga1 = ga0 + (size_t)16 * DK;
  int bu0 = cb + seg0 * 16 + srow;       if (bu0 > NU - 1) bu0 = NU - 1;
  int bu1 = cb + (seg0 + 1) * 16 + srow; if (bu1 > NU - 1) bu1 = NU - 1;
  const unsigned short* gb0 = Bm + (size_t)bu0 * DK + scol * 8;
  const unsigned short* gb1 = Bm + (size_t)bu1 * DK + scol * 8;
  unsigned short* la0 = As + (seg0) * 512;
  unsigned short* la1 = As + (seg0 + 1) * 512;
  unsigned short* lb0 = Bs + (seg0) * 512;
  unsigned short* lb1 = Bs + (seg0 + 1) * 512;

  for (int kb = 0; kb < DK; kb += 32) {
    __builtin_amdgcn_global_load_lds((__attribute__((address_space(1))) void*)(ga0 + kb),
                                     (__attribute__((address_space(3))) void*)la0, 16, 0, 0);
    __builtin_amdgcn_global_load_lds((__attribute__((address_space(1))) void*)(ga1 + kb),
                                     (__attribute__((address_space(3))) void*)la1, 16, 0, 0);
    __builtin_amdgcn_global_load_lds((__attribute__((address_space(1))) void*)(gb0 + kb),
                                     (__attribute__((address_space(3))) void*)lb0, 16, 0, 0);
    __builtin_amdgcn_global_load_lds((__attribute__((address_space(1))) void*)(gb1 + kb),
                                     (__attribute__((address_space(3))) void*)lb1, 16, 0, 0);
    __syncthreads();
    bf16x8 af[4], bfr[4];
    #pragma unroll
    for (int mi = 0; mi < 4; ++mi)
      af[mi] = *(const bf16x8*)&As[(wm * 64 + mi * 16 + l15) * 32 + q * 8];
    #pragma unroll
    for (int ni = 0; ni < 4; ++ni)
      bfr[ni] = *(const bf16x8*)&Bs[(wn * 64 + ni * 16 + l15) * 32 + q * 8];
    #pragma unroll
    for (int mi = 0; mi < 4; ++mi)
      #pragma unroll
      for (int ni = 0; ni < 4; ++ni)
        acc[mi][ni] = __builtin_amdgcn_mfma_f32_16x16x32_bf16(af[mi], bfr[ni], acc[mi][ni], 0, 0, 0);
    __syncthreads();
  }

  // ---- epilogue: per mi-slice, stage 32x128 exp-tile in LDS, write coalesced
  const bool full_panel = (cb + 128 <= NU);
  #pragma unroll
  for (int mi = 0; mi < 4; ++mi) {
    // Phase A: fragment -> LDS with bias + exp
    #pragma unroll
    for (int ni = 0; ni < 4; ++ni) {
      int col = cb + wn * 64 + ni * 16 + l15;
      int bcol = col < NU ? col : NU - 1;   // clamp: avoid OOB bias read
      float bv = bias[bcol];
      f32x4 c = acc[mi][ni];
      #pragma unroll
      for (int r = 0; r < 4; ++r)
        ot[(wm * 16 + q * 4 + r) * 132 + wn * 64 + ni * 16 + l15] = __expf(c[r] + bv);
    }
    __syncthreads();
    // Phase B: coalesced write-back + row sums. 8 threads/row, 16 floats each.
    {
      int lr = tid >> 3;          // 0..31 local row
      int sub = tid & 7;          // 0..7
      int grow = rb + (lr >> 4) * 64 + mi * 16 + (lr & 15);
      float* gout = out + (size_t)grow * NU + cb;
      const float* lrow = ot + lr * 132;
      float sum = 0.f;
      if (full_panel) {
        #pragma unroll
        for (int p = 0; p < 4; ++p) {
          int c = p * 32 + sub * 4;
          vf4 v = *(const vf4*)(lrow + c);
          sum += v.x + v.y + v.z + v.w;
          __builtin_nontemporal_store(v, (vf4*)(gout + c));
        }
      } else {
        #pragma unroll
        for (int p = 0; p < 4; ++p) {
          int c = p * 32 + sub * 4;
          #pragma unroll
          for (int e = 0; e < 4; ++e) {
            if (cb + c + e < NU) {
              float v = lrow[c + e];
              sum += v;
              __builtin_nontemporal_store(v, gout + c + e);
            }
          }
        }
      }
      sum += __shfl_xor(sum, 1, 64);
      sum += __shfl_xor(sum, 2, 64);
      sum += __shfl_xor(sum, 4, 64);
      if (sub == 0) atomicAdd(&row_sum[grow], sum);
    }
    __syncthreads();
  }
}

// ---------- sampled GEMM: fused exp-sum with accidental-hit masking ----------
__global__ __launch_bounds__(256) void gemm_sampled(
    const unsigned short* __restrict__ A, const unsigned short* __restrict__ SW,
    const float* __restrict__ adj, const int* __restrict__ sampled,
    const int* __restrict__ targets, float* __restrict__ loss_acc) {
  __shared__ alignas(16) unsigned short As[128 * 32];
  __shared__ alignas(16) unsigned short Bs[128 * 32];
  const int tid = threadIdx.x;
  const int wave = tid >> 6, lane = tid & 63;
  const int bid = blockIdx.x;
  const int sb = (bid & 7) * 128 + (bid >> 3);
  const int rb = (sb & 15) << 7;
  const int cb = (sb >> 4) << 7;
  const int wm = wave & 1, wn = wave >> 1;
  const int q = lane >> 4, l15 = lane & 15;
  const int srow = lane >> 2, scol = lane & 3;

  f32x4 acc[4][4] = {};

  const int seg0 = wave * 2;
  const unsigned short* ga0 = A + (size_t)(rb + seg0 * 16 + srow) * DK + scol * 8;
  const unsigned short* ga1 = ga0 + (size_t)16 * DK;
  const unsigned short* gb0 = SW + (size_t)(cb + seg0 * 16 + srow) * DK + scol * 8;
  const unsigned short* gb1 = gb0 + (size_t)16 * DK;
  unsigned short* la0 = &As[(seg0) * 512];
  unsigned short* la1 = &As[(seg0 + 1) * 512];
  unsigned short* lb0 = &Bs[(seg0) * 512];
  unsigned short* lb1 = &Bs[(seg0 + 1) * 512];

  for (int kb = 0; kb < DK; kb += 32) {
    __builtin_amdgcn_global_load_lds((__attribute__((address_space(1))) void*)(ga0 + kb),
                                     (__attribute__((address_space(3))) void*)la0, 16, 0, 0);
    __builtin_amdgcn_global_load_lds((__attribute__((address_space(1))) void*)(ga1 + kb),
                                     (__attribute__((address_space(3))) void*)la1, 16, 0, 0);
    __builtin_amdgcn_global_load_lds((__attribute__((address_space(1))) void*)(gb0 + kb),
                                     (__attribute__((address_space(3))) void*)lb0, 16, 0, 0);
    __builtin_amdgcn_global_load_lds((__attribute__((address_space(1))) void*)(gb1 + kb),
                                     (__attribute__((address_space(3))) void*)lb1, 16, 0, 0);
    __syncthreads();
    bf16x8 af[4], bfr[4];
    #pragma unroll
    for (int mi = 0; mi < 4; ++mi)
      af[mi] = *(const bf16x8*)&As[(wm * 64 + mi * 16 + l15) * 32 + q * 8];
    #pragma unroll
    for (int ni = 0; ni < 4; ++ni)
      bfr[ni] = *(const bf16x8*)&Bs[(wn * 64 + ni * 16 + l15) * 32 + q * 8];
    #pragma unroll
    for (int mi = 0; mi < 4; ++mi)
      #pragma unroll
      for (int ni = 0; ni < 4; ++ni)
        acc[mi][ni] = __builtin_amdgcn_mfma_f32_16x16x32_bf16(af[mi], bfr[ni], acc[mi][ni], 0, 0, 0);
    __syncthreads();
  }

  #pragma unroll
  for (int mi = 0; mi < 4; ++mi) {
    int row0 = rb + wm * 64 + mi * 16 + q * 4;
    int t0 = targets[row0], t1 = targets[row0 + 1], t2 = targets[row0 + 2], t3 = targets[row0 + 3];
    float rs[4] = {0.f, 0.f, 0.f, 0.f};
    #pragma unroll
    for (int ni = 0; ni < 4; ++ni) {
      int col = cb + wn * 64 + ni * 16 + l15;
      float av = adj[col];
      int sid = sampled[col];
      f32x4 c = acc[mi][ni];
      rs[0] += (sid == t0) ? 0.f : __expf(c[0] + av);
      rs[1] += (sid == t1) ? 0.f : __expf(c[1] + av);
      rs[2] += (sid == t2) ? 0.f : __expf(c[2] + av);
      rs[3] += (sid == t3) ? 0.f : __expf(c[3] + av);
    }
    #pragma unroll
    for (int r = 0; r < 4; ++r) {
      float v = rs[r];
      v += __shfl_xor(v, 1, 64);
      v += __shfl_xor(v, 2, 64);
      v += __shfl_xor(v, 4, 64);
      v += __shfl_xor(v, 8, 64);
      if (l15 == 0) atomicAdd(&loss_acc[row0 + r], v);
    }
  }
}

// ---------- 1/row_sum ----------
__global__ void prep_inv(const float* __restrict__ row_sum, float* __restrict__ inv) {
  int i = blockIdx.x * 256 + threadIdx.x;
  if (i < N_ROWS) inv[i] = 1.0f / row_sum[i];
}

// ---------- scale probs in place (nt: pure stream, no reuse) ----------
__global__ void scale_probs(float* __restrict__ out, const float* __restrict__ inv, unsigned n4) {
  unsigned i = blockIdx.x * 256u + threadIdx.x;
  if (i >= n4) return;
  constexpr unsigned long long MAGIC = ((1ull << 45) + 50256ull) / 50257ull;
  vf4 v = __builtin_nontemporal_load((const vf4*)out + i);
  unsigned long long base = (unsigned long long)i * 4ull;
  unsigned r0 = (unsigned)((base * MAGIC) >> 45);
  unsigned r1 = (unsigned)(((base + 1) * MAGIC) >> 45);
  unsigned r2 = (unsigned)(((base + 2) * MAGIC) >> 45);
  unsigned r3 = (unsigned)(((base + 3) * MAGIC) >> 45);
  v.x *= inv[r0]; v.y *= inv[r1]; v.z *= inv[r2]; v.w *= inv[r3];
  __builtin_nontemporal_store(v, (vf4*)out + i);
}

// ---------- final loss reduce ----------
__global__ void finalize_loss(const float* __restrict__ loss_acc,
                              const float* __restrict__ true_logit,
                              float* __restrict__ loss_out) {
  __shared__ float red[256];
  float s = 0.f;
  for (int i = threadIdx.x; i < N_ROWS; i += 256)
    s += logf(loss_acc[i]) - true_logit[i];
  red[threadIdx.x] = s;
  __syncthreads();
  for (int off = 128; off > 0; off >>= 1) {
    if (threadIdx.x < off) red[threadIdx.x] += red[threadIdx.x + off];
    __syncthreads();
  }
  if (threadIdx.x == 0) loss_out[0] = red[0] / (float)N_ROWS;
}

extern "C" void kernel_launch(void* const* d_in, const int* in_sizes, int n_in,
                              void* d_out, int out_size, void* d_ws, size_t ws_size,
                              hipStream_t stream) {
  const float* x = (const float*)d_in[0];       // [2,1024,1024]
  const float* kern = (const float*)d_in[1];    // [50257,1024]
  const float* bias = (const float*)d_in[2];    // [50257]
  const int* targets = (const int*)d_in[3];     // [2048]
  const int* sampled = (const int*)d_in[4];     // [8192]
  float* out = (float*)d_out;                   // probs [2048*50257] then loss [1]

  char* ws = (char*)d_ws;
  size_t off = 0;
  unsigned short* kbf = (unsigned short*)(ws + off); off += (size_t)NU * DK * 2;     // 98.2 MiB
  unsigned short* xbf = (unsigned short*)(ws + off); off += (size_t)N_ROWS * DK * 2; // 4 MiB
  unsigned short* swbf = (unsigned short*)(ws + off); off += (size_t)NS * DK * 2;    // 16 MiB
  float* adj = (float*)(ws + off); off += (size_t)NS * 4;
  float* row_sum = (float*)(ws + off); off += (size_t)N_ROWS * 4;
  float* inv_rs = (float*)(ws + off); off += (size_t)N_ROWS * 4;
  float* loss_acc = (float*)(ws + off); off += (size_t)N_ROWS * 4;
  float* true_l = (float*)(ws + off); off += (size_t)N_ROWS * 4;

  hipMemsetAsync(row_sum, 0, N_ROWS * 4, stream);
  hipMemsetAsync(loss_acc, 0, N_ROWS * 4, stream);

  {
    unsigned n = NU * DK;  // 51,463,168 (divisible by 8)
    cvt_f32_bf16<<<(n / 8 + 255) / 256, 256, 0, stream>>>(kern, kbf, n);
  }
  {
    unsigned n = N_ROWS * DK;
    cvt_f32_bf16<<<(n / 8 + 255) / 256, 256, 0, stream>>>(x, xbf, n);
  }
  gather_sampled<<<NS, 256, 0, stream>>>(kern, bias, sampled, swbf, adj);
  true_logits_k<<<N_ROWS / 4, 256, 0, stream>>>(x, kern, bias, targets, true_l, loss_acc);

  // 393 col panels x 16 row tiles = 6288 blocks (= 8 XCD chunks of 786)
  gemm_probs<<<dim3(6288), 256, 0, stream>>>(xbf, kbf, bias, out, row_sum);

  // 64 col panels x 16 row tiles = 1024 blocks (= 8 XCD chunks of 128)
  gemm_sampled<<<dim3(1024), 256, 0, stream>>>(xbf, swbf, adj, sampled, targets, loss_acc);

  prep_inv<<<(N_ROWS + 255) / 256, 256, 0, stream>>>(row_sum, inv_rs);

  {
    unsigned n4 = (unsigned)(((size_t)N_ROWS * NU) / 4);  // 25,731,584 (exact)
    scale_probs<<<(n4 + 255u) / 256u, 256, 0, stream>>>(out, inv_rs, n4);
  }
  finalize_loss<<<1, 256, 0, stream>>>(loss_acc, true_l, out + (size_t)N_ROWS * NU);
}